// Round 16
// baseline (157.359 us; speedup 1.0000x reference)
//
#include <hip/hip_runtime.h>
#include <hip/hip_bf16.h>
#include <math.h>

#define BB 8192
#define XD 784
#define ZD 10
#define KK 2000
#define HH 300

typedef short short8 __attribute__((ext_vector_type(8)));
typedef float f32x4 __attribute__((ext_vector_type(4)));

__device__ __forceinline__ float sp_(float x) {
    return fmaxf(x, 0.f) + __logf(1.f + __expf(-fabsf(x)));
}
__device__ __forceinline__ float elu_(float x) { return x > 0.f ? x : __expf(x) - 1.f; }
__device__ __forceinline__ unsigned short bf16_(float v) {
    __hip_bfloat16 h = __float2bfloat16(v);
    return __builtin_bit_cast(unsigned short, h);
}
__device__ __forceinline__ float b2f_(unsigned short u) {
    return __builtin_bit_cast(float, (unsigned int)u << 16);
}
__device__ __forceinline__ short8 ld8_(const unsigned short* p) {
    return *reinterpret_cast<const short8*>(p);
}
// fragment-major addr of (row<16, k): slice k>>5, lane = row + ((k>>3)&3)*16
__device__ __forceinline__ int fma16_(int row, int k) {
    return (((k >> 5) * 64) + row + (((k >> 3) & 3) << 4)) * 8 + (k & 7);
}

// ---------------------------------------------------------------------------
// ki-major layer on a 16-row slab: C[16][NI*128] = A[16][KP] @ Wt[.][KP]^T.
// 8 waves, wave w owns cols {ni*128 + w*16..+15}; acc[NI] across layer;
// A and B double-buffered per ki (A may be LDS or GLOBAL frag-major — same
// indexing). Epilogue ONCE per layer, biases read from global. No cross-lane
// ops in loops.
// LMODE 0: bf16 elu -> actout (guard c<320). LMODE 1: fp32 c3L (c<20).
// LMODE 2: per-row sum(x*logit - softplus(logit)), x fp32 global -> redL.
// ---------------------------------------------------------------------------
template<int LMODE, int KP, int KI, int NI>
__device__ __forceinline__ void layer16(
    const int tid,
    const unsigned short* __restrict__ actin,   // frag-major (LDS or global)
    const unsigned short* __restrict__ Wt,
    const float* __restrict__ bias,             // global
    unsigned short* __restrict__ actout,        // LDS (LMODE 0)
    float* __restrict__ c3L,                    // LDS (LMODE 1)
    float* __restrict__ redL,                   // LDS (LMODE 2)
    const float* __restrict__ xrow)             // global x slab base (LMODE 2)
{
    const int w = tid >> 6, l = tid & 63;
    const int cl = l & 15, hi = l >> 4, g4 = hi << 2;
    const unsigned short* bp = Wt + (size_t)(w * 16 + cl) * KP + hi * 8;

    f32x4 acc[NI];
    #pragma unroll
    for (int ni = 0; ni < NI; ++ni) acc[ni] = (f32x4){0.f, 0.f, 0.f, 0.f};

    short8 Bb[2][NI][2];
    short8 Ab[2][2];
    #pragma unroll
    for (int ni = 0; ni < NI; ++ni) {
        Bb[0][ni][0] = ld8_(bp + (size_t)ni * 128 * KP);
        Bb[0][ni][1] = ld8_(bp + (size_t)ni * 128 * KP + 32);
    }
    Ab[0][0] = ld8_(actin + (0 * 64 + l) * 8);
    Ab[0][1] = ld8_(actin + (1 * 64 + l) * 8);

    #pragma unroll
    for (int ki = 0; ki < KI; ++ki) {
        const int cur = ki & 1, nxt = cur ^ 1;
        if (ki + 1 < KI) {
            #pragma unroll
            for (int ni = 0; ni < NI; ++ni) {
                Bb[nxt][ni][0] = ld8_(bp + (ki + 1) * 64 + (size_t)ni * 128 * KP);
                Bb[nxt][ni][1] = ld8_(bp + (ki + 1) * 64 + (size_t)ni * 128 * KP + 32);
            }
            Ab[nxt][0] = ld8_(actin + (((ki + 1) * 2 + 0) * 64 + l) * 8);
            Ab[nxt][1] = ld8_(actin + (((ki + 1) * 2 + 1) * 64 + l) * 8);
        }
        #pragma unroll
        for (int ni = 0; ni < NI; ++ni) {
            acc[ni] = __builtin_amdgcn_mfma_f32_16x16x32_bf16(Ab[cur][0], Bb[cur][ni][0], acc[ni], 0, 0, 0);
            acc[ni] = __builtin_amdgcn_mfma_f32_16x16x32_bf16(Ab[cur][1], Bb[cur][ni][1], acc[ni], 0, 0, 0);
        }
    }

    if constexpr (LMODE == 0) {
        #pragma unroll
        for (int ni = 0; ni < NI; ++ni) {
            const int c = ni * 128 + w * 16 + cl;
            const float bb = (c < HH) ? bias[c] : 0.f;
            #pragma unroll
            for (int rr = 0; rr < 4; ++rr) {
                float o = (c < HH) ? elu_(acc[ni][rr] + bb) : 0.f;
                if (c < 320)
                    actout[(((c >> 5) * 64) + (g4 + rr) + (((c >> 3) & 3) << 4)) * 8 + (c & 7)] = bf16_(o);
            }
        }
    } else if constexpr (LMODE == 1) {
        const int c = w * 16 + cl;
        if (c < 20) {
            #pragma unroll
            for (int rr = 0; rr < 4; ++rr)
                c3L[(g4 + rr) * 24 + c] = acc[0][rr] + bias[c];
        }
    } else {
        float rs[4] = {0.f, 0.f, 0.f, 0.f};
        #pragma unroll
        for (int ni = 0; ni < NI; ++ni) {
            const int c = ni * 128 + w * 16 + cl;
            if (c < XD) {
                const float bb = bias[c];
                #pragma unroll
                for (int rr = 0; rr < 4; ++rr) {
                    float lv = acc[ni][rr] + bb;
                    float xv = xrow[(size_t)(g4 + rr) * XD + c];
                    rs[rr] += xv * lv - sp_(lv);
                }
            }
        }
        #pragma unroll
        for (int rr = 0; rr < 4; ++rr) {
            float s = rs[rr];
            s += __shfl_xor(s, 1); s += __shfl_xor(s, 2);
            s += __shfl_xor(s, 4); s += __shfl_xor(s, 8);
            if (cl == 0) redL[(g4 + rr) * 8 + w] = s;
        }
    }
}

// ---------------------------------------------------------------------------
// KI=1 layers (KP=64, A in regs once), ni-major, B prefetched one ni ahead.
// LMODE 0: dec1 elu stores. LMODE 3: comp — per-lane online logsumexp over
// ni (no cross-lane ops); per-wave (m,s) -> redM/redS[row][wave].
// ---------------------------------------------------------------------------
template<int LMODE, int NI>
__device__ __forceinline__ void layerN16(
    const int tid,
    const unsigned short* __restrict__ actin,   // fbL (LDS, 2 slices)
    const unsigned short* __restrict__ Wt,
    const float* __restrict__ bias,             // global
    unsigned short* __restrict__ actout,
    float* __restrict__ redM, float* __restrict__ redS)
{
    const int w = tid >> 6, l = tid & 63;
    const int cl = l & 15, hi = l >> 4, g4 = hi << 2;
    const unsigned short* bp = Wt + (size_t)(w * 16 + cl) * 64 + hi * 8;

    short8 a0 = ld8_(actin + (0 * 64 + l) * 8);
    short8 a1 = ld8_(actin + (1 * 64 + l) * 8);

    float rA[4], rB[4];
    #pragma unroll
    for (int rr = 0; rr < 4; ++rr) { rA[rr] = -1e30f; rB[rr] = 0.f; }

    short8 c0 = ld8_(bp), c1 = ld8_(bp + 32);
    #pragma unroll
    for (int ni = 0; ni < NI; ++ni) {
        short8 p0 = c0, p1 = c1;
        if (ni + 1 < NI) {
            p0 = ld8_(bp + (size_t)(ni + 1) * 128 * 64);
            p1 = ld8_(bp + (size_t)(ni + 1) * 128 * 64 + 32);
        }
        f32x4 acc = __builtin_amdgcn_mfma_f32_16x16x32_bf16(a0, c0, (f32x4){0.f, 0.f, 0.f, 0.f}, 0, 0, 0);
        acc = __builtin_amdgcn_mfma_f32_16x16x32_bf16(a1, c1, acc, 0, 0, 0);
        if constexpr (LMODE == 0) {
            const int c = ni * 128 + w * 16 + cl;
            const float bb = (c < HH) ? bias[c] : 0.f;
            #pragma unroll
            for (int rr = 0; rr < 4; ++rr) {
                float o = (c < HH) ? elu_(acc[rr] + bb) : 0.f;
                if (c < 320)
                    actout[(((c >> 5) * 64) + (g4 + rr) + (((c >> 3) & 3) << 4)) * 8 + (c & 7)] = bf16_(o);
            }
        } else {
            #pragma unroll
            for (int rr = 0; rr < 4; ++rr) {
                float v = acc[rr];
                float mx = fmaxf(v, rA[rr]);
                rB[rr] = rB[rr] * __expf(rA[rr] - mx) + __expf(v - mx);
                rA[rr] = mx;
            }
        }
        c0 = p0; c1 = p1;
    }
    if constexpr (LMODE == 3) {
        if (cl == 0) {
            #pragma unroll
            for (int rr = 0; rr < 4; ++rr) {
                redM[(g4 + rr) * 8 + w] = rA[rr];
                redS[(g4 + rr) * 8 + w] = rB[rr];
            }
        }
    }
}

__global__ __launch_bounds__(512, 4)
void fused_k(const float* __restrict__ xg,
             const unsigned short* __restrict__ xg2,
             const unsigned short* __restrict__ w1t, const float* __restrict__ eb1,
             const unsigned short* __restrict__ w2t, const float* __restrict__ eb2,
             const unsigned short* __restrict__ w3t, const float* __restrict__ eb3,
             const unsigned short* __restrict__ d1t, const float* __restrict__ db1,
             const unsigned short* __restrict__ d2t, const float* __restrict__ db2,
             const unsigned short* __restrict__ d3t, const float* __restrict__ db3,
             const unsigned short* __restrict__ G,
             const float* __restrict__ eps, float* __restrict__ part)
{
    __shared__ __align__(16) unsigned short actP[5120];   // 16x320 frag-major
    __shared__ __align__(16) unsigned short actQ[5120];
    __shared__ __align__(16) unsigned short fbL[1024];    // 16x64
    __shared__ float c3L[384];
    __shared__ float redM[128], redS[128], redL[128], lqzL[16];

    const int tid = threadIdx.x;
    const int m0 = blockIdx.x * 16;
    const unsigned short* Aslab = xg2 + (size_t)blockIdx.x * 13312;  // 26*512

    // zero ALL of fbL: sizeof(fbL)=2048B = 128 uint4  (r13/r15 bug class)
    if (tid < 128) reinterpret_cast<uint4*>(fbL)[tid] = (uint4){0u, 0u, 0u, 0u};
    __syncthreads();

    layer16<0, 832, 13, 3>(tid, Aslab, w1t, eb1, actP, nullptr, nullptr, nullptr);
    __syncthreads();
    layer16<0, 320, 5, 3>(tid, actP, w2t, eb2, actQ, nullptr, nullptr, nullptr);
    __syncthreads();
    layer16<1, 320, 5, 1>(tid, actQ, w3t, eb3, nullptr, c3L, nullptr, nullptr);
    __syncthreads();

    if (tid < 16) {
        float a = 0.f;
        #pragma unroll
        for (int j = 0; j < ZD; ++j) {
            float qm = c3L[tid * 24 + j];
            float qh = c3L[tid * 24 + 10 + j];
            float qv = sp_(qh) + 1e-8f;
            float e  = eps[(size_t)(m0 + tid) * ZD + j];
            float zj = qm + sqrtf(qv) * e;
            fbL[fma16_(tid, j)]      = bf16_(zj * zj);
            fbL[fma16_(tid, 10 + j)] = bf16_(zj);
            float d = zj - qm;
            a += __logf(6.283185307179586f * qv) + d * d / qv;
        }
        fbL[fma16_(tid, 20)] = bf16_(1.f);   // picks up c_k hi/lo from G cols 20/21
        fbL[fma16_(tid, 21)] = bf16_(1.f);
        lqzL[tid] = -0.5f * a;
    }
    __syncthreads();

    layerN16<0, 3>(tid, fbL, d1t, db1, actP, nullptr, nullptr);
    __syncthreads();
    layer16<0, 320, 5, 3>(tid, actP, d2t, db2, actQ, nullptr, nullptr, nullptr);
    __syncthreads();
    layer16<2, 320, 5, 7>(tid, actQ, d3t, db3, nullptr, nullptr, redL,
                          xg + (size_t)m0 * XD);
    __syncthreads();
    layerN16<3, 16>(tid, fbL, G, nullptr, nullptr, redM, redS);
    __syncthreads();

    if (tid < 16) {
        float M = -1e30f, S = 0.f;
        #pragma unroll
        for (int w8 = 0; w8 < 8; ++w8) {
            float m = redM[tid * 8 + w8], s = redS[tid * 8 + w8];
            float M2 = fmaxf(M, m);
            S = S * __expf(M - M2) + s * __expf(m - M2);
            M = M2;
        }
        float lpz = M + __logf(S) - 7.6009024595420824f;  // log(2000)
        float lpx = 0.f;
        #pragma unroll
        for (int w8 = 0; w8 < 8; ++w8) lpx += redL[tid * 8 + w8];
        float kl = lqzL[tid] - lpz;
        float ne = kl - lpx, re = -lpx;
        #pragma unroll
        for (int d = 1; d <= 8; d <<= 1) {
            ne += __shfl_xor(ne, d); kl += __shfl_xor(kl, d); re += __shfl_xor(re, d);
        }
        if (tid == 0) {
            part[blockIdx.x * 3 + 0] = ne;
            part[blockIdx.x * 3 + 1] = kl;
            part[blockIdx.x * 3 + 2] = re;
        }
    }
}

// weight transposes/pads + GMM coef + x -> bf16 frag-major (xg2)
__global__ __launch_bounds__(256)
void prep_k(const float* __restrict__ x,
            const float* __restrict__ ew1, const float* __restrict__ ew2,
            const float* __restrict__ ew3, const float* __restrict__ dw1,
            const float* __restrict__ dw2, const float* __restrict__ dw3,
            const float* __restrict__ zpre,
            unsigned short* __restrict__ w1t, unsigned short* __restrict__ w2t,
            unsigned short* __restrict__ w3t, unsigned short* __restrict__ d1t,
            unsigned short* __restrict__ d2t, unsigned short* __restrict__ d3t,
            unsigned short* __restrict__ G, unsigned short* __restrict__ xg2)
{
    const int idx = blockIdx.x * 256 + threadIdx.x;
    const int y = blockIdx.y;
    if (y == 0) {
        if (idx >= 384 * 832) return;
        int n = idx / 832, k = idx - n * 832;
        w1t[idx] = bf16_((n < HH && k < XD) ? ew1[(size_t)k * HH + n] : 0.f);
    } else if (y == 1) {
        if (idx >= 384 * 320) return;
        int n = idx / 320, k = idx - n * 320;
        w2t[idx] = bf16_((n < HH && k < HH) ? ew2[(size_t)k * HH + n] : 0.f);
    } else if (y == 2) {
        if (idx >= 128 * 320) return;
        int n = idx / 320, k = idx - n * 320;
        w3t[idx] = bf16_((n < 2 * ZD && k < HH) ? ew3[(size_t)k * 2 * ZD + n] : 0.f);
    } else if (y == 3) {   // d1t [384][64]; dw1 rows at k=10..19 (fb layout)
        if (idx >= 384 * 64) return;
        int n = idx / 64, k = idx - n * 64;
        float v = (n < HH && k >= 10 && k < 20) ? dw1[(size_t)(k - 10) * HH + n] : 0.f;
        d1t[idx] = bf16_(v);
    } else if (y == 4) {
        if (idx >= 384 * 320) return;
        int n = idx / 320, k = idx - n * 320;
        d2t[idx] = bf16_((n < HH && k < HH) ? dw2[(size_t)k * HH + n] : 0.f);
    } else if (y == 5) {
        if (idx >= 896 * 320) return;
        int n = idx / 320, k = idx - n * 320;
        d3t[idx] = bf16_((n < XD && k < HH) ? dw3[(size_t)k * XD + n] : 0.f);
    } else if (y == 6) {
        if (idx >= 2048) return;
        int k = idx;
        if (k < KK) {
            float csum = 0.f;
            #pragma unroll
            for (int j = 0; j < ZD; ++j) {
                float m = zpre[k * ZD + j];
                float h = zpre[(KK + k) * ZD + j];
                float v = sp_(h) + 1e-8f;
                G[k * 64 + j] = bf16_(-0.5f / v);
                G[k * 64 + 10 + j] = bf16_(m / v);
                csum += __logf(6.283185307179586f * v) + m * m / v;
            }
            float ck = -0.5f * csum;
            unsigned short hic = bf16_(ck);
            G[k * 64 + 20] = hic;
            G[k * 64 + 21] = bf16_(ck - b2f_(hic));
            #pragma unroll
            for (int j = 22; j < 64; ++j) G[k * 64 + j] = 0;
        } else {
            #pragma unroll
            for (int j = 0; j < 20; ++j) G[k * 64 + j] = 0;
            G[k * 64 + 20] = bf16_(-1e30f);
            G[k * 64 + 21] = 0;
            #pragma unroll
            for (int j = 22; j < 64; ++j) G[k * 64 + j] = 0;
        }
    } else {
        // xg2: 512 slabs x 26 slices x 64 lanes x 8 elems (bf16 frag-major)
        if (idx >= 512 * 26 * 64) return;
        const int ln = idx & 63;
        const int t = idx >> 6;
        const int sl = t % 26;
        const int slab = t / 26;
        const int row = slab * 16 + (ln & 15);
        const int k0 = sl * 32 + (ln >> 4) * 8;
        short8 v8 = (short8){0, 0, 0, 0, 0, 0, 0, 0};
        if (k0 < XD) {
            const float* src = x + (size_t)row * XD + k0;
            float4 f0 = *reinterpret_cast<const float4*>(src);
            float4 f1 = *reinterpret_cast<const float4*>(src + 4);
            v8[0] = (short)bf16_(f0.x); v8[1] = (short)bf16_(f0.y);
            v8[2] = (short)bf16_(f0.z); v8[3] = (short)bf16_(f0.w);
            v8[4] = (short)bf16_(f1.x); v8[5] = (short)bf16_(f1.y);
            v8[6] = (short)bf16_(f1.z); v8[7] = (short)bf16_(f1.w);
        }
        *reinterpret_cast<short8*>(&xg2[(size_t)idx * 8]) = v8;
    }
}

__global__ void fin_k(const float* __restrict__ part, float* __restrict__ out)
{
    int c = threadIdx.x >> 6, l = threadIdx.x & 63;
    if (c < 3) {
        float s = 0.f;
        for (int i = l; i < 512; i += 64) s += part[i * 3 + c];
        #pragma unroll
        for (int d = 1; d < 64; d <<= 1) s += __shfl_xor(s, d);
        if (l == 0) out[c] = s / (float)BB;
    }
}

extern "C" void kernel_launch(void* const* d_in, const int* in_sizes, int n_in,
                              void* d_out, int out_size, void* d_ws, size_t ws_size,
                              hipStream_t stream)
{
    const float* x    = (const float*)d_in[0];
    const float* eps  = (const float*)d_in[1];
    const float* zpre = (const float*)d_in[2];
    const float* ew1  = (const float*)d_in[3];
    const float* eb1  = (const float*)d_in[4];
    const float* ew2  = (const float*)d_in[5];
    const float* eb2  = (const float*)d_in[6];
    const float* ew3  = (const float*)d_in[7];
    const float* eb3  = (const float*)d_in[8];
    const float* dw1  = (const float*)d_in[9];
    const float* db1  = (const float*)d_in[10];
    const float* dw2  = (const float*)d_in[11];
    const float* db2  = (const float*)d_in[12];
    const float* dw3  = (const float*)d_in[13];
    const float* db3  = (const float*)d_in[14];
    float* out = (float*)d_out;

    float* ws   = (float*)d_ws;
    float* part = ws;                        // 512*3
    unsigned short* ub = (unsigned short*)(part + 1536);
    unsigned short* xg2 = ub; ub += (size_t)BB * 832;
    unsigned short* w1t = ub; ub += 384 * 832;
    unsigned short* w2t = ub; ub += 384 * 320;
    unsigned short* w3t = ub; ub += 128 * 320;
    unsigned short* d1t = ub; ub += 384 * 64;
    unsigned short* d2t = ub; ub += 384 * 320;
    unsigned short* d3t = ub; ub += 896 * 320;
    unsigned short* G   = ub; ub += 2048 * 64;

    dim3 blk(256);
    prep_k<<<dim3(3328, 8), blk, 0, stream>>>(x, ew1, ew2, ew3, dw1, dw2, dw3, zpre,
                                              w1t, w2t, w3t, d1t, d2t, d3t, G, xg2);
    fused_k<<<512, 512, 0, stream>>>(x, xg2, w1t, eb1, w2t, eb2, w3t, eb3,
                                     d1t, db1, d2t, db2, d3t, db3, G, eps, part);
    fin_k<<<1, 256, 0, stream>>>(part, out);
}

// Round 17
// 90.850 us; speedup vs baseline: 1.7321x; 1.7321x over previous
//
#include <hip/hip_runtime.h>
#include <hip/hip_bf16.h>
#include <math.h>

#define BB 8192
#define XD 784
#define ZD 10
#define KK 2000
#define HH 300

typedef short short8 __attribute__((ext_vector_type(8)));
typedef float f32x4 __attribute__((ext_vector_type(4)));

__device__ __forceinline__ float sp_(float x) {
    return fmaxf(x, 0.f) + __logf(1.f + __expf(-fabsf(x)));
}
__device__ __forceinline__ float elu_(float x) { return x > 0.f ? x : __expf(x) - 1.f; }
__device__ __forceinline__ unsigned short bf16_(float v) {
    __hip_bfloat16 h = __float2bfloat16(v);
    return __builtin_bit_cast(unsigned short, h);
}
__device__ __forceinline__ float b2f_(unsigned short u) {
    return __builtin_bit_cast(float, (unsigned int)u << 16);
}
__device__ __forceinline__ short8 ld8_(const unsigned short* p) {
    return *reinterpret_cast<const short8*>(p);
}
__device__ __forceinline__ void gl16(const unsigned short* g, unsigned short* l) {
    __builtin_amdgcn_global_load_lds(
        (const __attribute__((address_space(1))) unsigned int*)g,
        (__attribute__((address_space(3))) unsigned int*)l, 16, 0, 0);
}
template<int N> __device__ __forceinline__ void vwait() {
    if constexpr (N == 0) asm volatile("s_waitcnt vmcnt(0)" ::: "memory");
    if constexpr (N == 2) asm volatile("s_waitcnt vmcnt(2)" ::: "memory");
    if constexpr (N == 4) asm volatile("s_waitcnt vmcnt(4)" ::: "memory");
    if constexpr (N == 6) asm volatile("s_waitcnt vmcnt(6)" ::: "memory");
}
// fragment-major write of element (row<32, k) into 2-rowgroup buffer, KS=2
__device__ __forceinline__ void fbw(unsigned short* fb, int row, int k, unsigned short v) {
    fb[(((row >> 4) * 2 + (k >> 5)) * 64 + (row & 15) + (((k >> 3) & 3) << 4)) * 8 + (k & 7)] = v;
}

// ---------------------------------------------------------------------------
// Unified streamed layer on a 32-row slab: C[32][NI*128] = A @ Wt^T.
// 8 waves, wave w owns cols {ni*128 + w*16..+15}. ni-outer / ki-inner, FULLY
// UNROLLED. B staged per (ni,ki) step (2KB) into a WAVE-PRIVATE 3-slot LDS
// ring via global_load_lds; prefetch distance 3; counted vmcnt(6/4/2/0);
// NO barriers inside the layer. A via ds_read (doesn't touch vmcnt).
// Epilogue per ni (compile-time folded), bias loads from global (only
// over-wait vmcnt, never under-wait: vmcnt drains oldest-first).
// LMODE 0: bf16 elu -> actout (store c<320). LMODE 1: fp32 c3L (c<20).
// LMODE 2: per-row sum(x*logit - softplus(logit)), x from LDS xs -> redL.
// LMODE 3: per-lane online logsumexp over ni -> redM/redS (c_k via cols 20/21).
// ---------------------------------------------------------------------------
template<int LMODE, int KP, int KI, int NI>
__device__ __forceinline__ void layerS(
    const int tid,
    const unsigned short* __restrict__ xs,
    const unsigned short* __restrict__ actin,
    const unsigned short* __restrict__ Wt,
    const float* __restrict__ bias,
    unsigned short* __restrict__ actout,
    float* __restrict__ c3L, float* __restrict__ redL,
    float* __restrict__ redM, float* __restrict__ redS,
    unsigned short* __restrict__ ring)
{
    const int w = tid >> 6, l = tid & 63;
    const int cl = l & 15, hi = l >> 4, g4 = hi << 2;
    constexpr int KS = KP / 32;
    constexpr int NQ = NI * KI;
    unsigned short* ringW = ring + w * 3072;               // 3 slots x 1024 sh
    const unsigned short* bsrc = Wt + (size_t)(w * 16 + cl) * KP + hi * 8;

    f32x4 acc[2];
    float rA[2][4], rB[2][4];
    #pragma unroll
    for (int rg = 0; rg < 2; ++rg)
        #pragma unroll
        for (int rr = 0; rr < 4; ++rr) {
            rA[rg][rr] = (LMODE == 3) ? -1e30f : 0.f;
            rB[rg][rr] = 0.f;
        }

    auto STAGE = [&](int q) {
        const int ni = q / KI, ki = q % KI, slot = q % 3;
        const unsigned short* s0 = bsrc + (size_t)ni * 128 * KP + ki * 64;
        gl16(s0,      ringW + slot * 1024);
        gl16(s0 + 32, ringW + slot * 1024 + 512);
    };

    STAGE(0);
    if constexpr (NQ > 1) STAGE(1);
    if constexpr (NQ > 2) STAGE(2);

    #pragma unroll
    for (int q = 0; q < NQ; ++q) {
        const int ni = q / KI, ki = q % KI, slot = q % 3;
        if (ki == 0) {
            acc[0] = (f32x4){0.f, 0.f, 0.f, 0.f};
            acc[1] = (f32x4){0.f, 0.f, 0.f, 0.f};
        }
        const int rem = NQ - 1 - q;
        if (rem >= 3) vwait<6>();
        else if (rem == 2) vwait<4>();
        else if (rem == 1) vwait<2>();
        else vwait<0>();
        __builtin_amdgcn_sched_barrier(0);
        short8 b0 = ld8_(ringW + slot * 1024 + l * 8);
        short8 b1 = ld8_(ringW + slot * 1024 + 512 + l * 8);
        short8 a00 = ld8_(actin + ((0 * KS + ki * 2 + 0) * 64 + l) * 8);
        short8 a01 = ld8_(actin + ((0 * KS + ki * 2 + 1) * 64 + l) * 8);
        short8 a10 = ld8_(actin + ((1 * KS + ki * 2 + 0) * 64 + l) * 8);
        short8 a11 = ld8_(actin + ((1 * KS + ki * 2 + 1) * 64 + l) * 8);
        if (q + 3 < NQ) STAGE(q + 3);      // after reads of slot (same slot)
        acc[0] = __builtin_amdgcn_mfma_f32_16x16x32_bf16(a00, b0, acc[0], 0, 0, 0);
        acc[0] = __builtin_amdgcn_mfma_f32_16x16x32_bf16(a01, b1, acc[0], 0, 0, 0);
        acc[1] = __builtin_amdgcn_mfma_f32_16x16x32_bf16(a10, b0, acc[1], 0, 0, 0);
        acc[1] = __builtin_amdgcn_mfma_f32_16x16x32_bf16(a11, b1, acc[1], 0, 0, 0);

        if (ki == KI - 1) {
            const int c = ni * 128 + w * 16 + cl;
            if constexpr (LMODE == 0) {
                const float bb = (c < HH) ? bias[c] : 0.f;
                #pragma unroll
                for (int rg = 0; rg < 2; ++rg)
                    #pragma unroll
                    for (int rr = 0; rr < 4; ++rr) {
                        float o = (c < HH) ? elu_(acc[rg][rr] + bb) : 0.f;
                        if (c < 320)
                            actout[((rg * 10 + (c >> 5)) * 64 + (g4 + rr) + (((c >> 3) & 3) << 4)) * 8 + (c & 7)] = bf16_(o);
                    }
            } else if constexpr (LMODE == 1) {
                const int cc = w * 16 + cl;
                if (cc < 20) {
                    #pragma unroll
                    for (int rg = 0; rg < 2; ++rg)
                        #pragma unroll
                        for (int rr = 0; rr < 4; ++rr)
                            c3L[(rg * 16 + g4 + rr) * 24 + cc] = acc[rg][rr] + bias[cc];
                }
            } else if constexpr (LMODE == 2) {
                if (c < XD) {
                    const float bb = bias[c];
                    #pragma unroll
                    for (int rg = 0; rg < 2; ++rg)
                        #pragma unroll
                        for (int rr = 0; rr < 4; ++rr) {
                            float lv = acc[rg][rr] + bb;
                            float xv = b2f_(xs[((rg * 26 + (c >> 5)) * 64 + (g4 + rr) + (((c >> 3) & 3) << 4)) * 8 + (c & 7)]);
                            rA[rg][rr] += xv * lv - sp_(lv);
                        }
                }
            } else {
                #pragma unroll
                for (int rg = 0; rg < 2; ++rg)
                    #pragma unroll
                    for (int rr = 0; rr < 4; ++rr) {
                        float v = acc[rg][rr];
                        float mx = fmaxf(v, rA[rg][rr]);
                        rB[rg][rr] = rB[rg][rr] * __expf(rA[rg][rr] - mx) + __expf(v - mx);
                        rA[rg][rr] = mx;
                    }
            }
        }
    }

    if constexpr (LMODE == 2) {
        #pragma unroll
        for (int rg = 0; rg < 2; ++rg)
            #pragma unroll
            for (int rr = 0; rr < 4; ++rr) {
                float s = rA[rg][rr];
                s += __shfl_xor(s, 1); s += __shfl_xor(s, 2);
                s += __shfl_xor(s, 4); s += __shfl_xor(s, 8);
                if (cl == 0) redL[(rg * 16 + g4 + rr) * 8 + w] = s;
            }
    }
    if constexpr (LMODE == 3) {
        #pragma unroll
        for (int d = 1; d <= 8; d <<= 1)
            #pragma unroll
            for (int rg = 0; rg < 2; ++rg)
                #pragma unroll
                for (int rr = 0; rr < 4; ++rr) {
                    float mo = __shfl_xor(rA[rg][rr], d);
                    float so = __shfl_xor(rB[rg][rr], d);
                    float M = fmaxf(rA[rg][rr], mo);
                    rB[rg][rr] = rB[rg][rr] * __expf(rA[rg][rr] - M) + so * __expf(mo - M);
                    rA[rg][rr] = M;
                }
        if (cl == 0) {
            #pragma unroll
            for (int rg = 0; rg < 2; ++rg)
                #pragma unroll
                for (int rr = 0; rr < 4; ++rr) {
                    redM[(rg * 16 + g4 + rr) * 8 + w] = rA[rg][rr];
                    redS[(rg * 16 + g4 + rr) * 8 + w] = rB[rg][rr];
                }
        }
    }
}

__global__ __launch_bounds__(512, 2)
void fused_k(const float* __restrict__ xg,
             const unsigned short* __restrict__ w1t, const float* __restrict__ eb1,
             const unsigned short* __restrict__ w2t, const float* __restrict__ eb2,
             const unsigned short* __restrict__ w3t, const float* __restrict__ eb3,
             const unsigned short* __restrict__ d1t, const float* __restrict__ db1,
             const unsigned short* __restrict__ d2t, const float* __restrict__ db2,
             const unsigned short* __restrict__ d3t, const float* __restrict__ db3,
             const unsigned short* __restrict__ G,
             const float* __restrict__ eps, float* __restrict__ part)
{
    __shared__ __align__(16) unsigned short xs[26624];    // 32x832 bf16 frag-major
    __shared__ __align__(16) unsigned short actP[10240];  // 32x320
    __shared__ __align__(16) unsigned short actQ[10240];
    __shared__ __align__(16) unsigned short fbL[2048];    // 32x64
    __shared__ __align__(16) unsigned short ring[24576];  // 8 waves x 3 slots x 1024
    __shared__ float c3L[768];
    __shared__ float redM[256], redS[256], redL[256], lqzL[32];

    const int tid = threadIdx.x;
    const int m0 = blockIdx.x * 32;

    // stage x (fp32 -> bf16, fragment-major); zero ALL of fbL (4096B = 256 uint4)
    #pragma unroll
    for (int it = 0; it < 7; ++it) {
        const int c = tid + it * 512;
        if (c < 32 * 104) {
            const int row = c / 104, kc = c - row * 104;
            const int k0 = kc * 8;
            short8 v8 = (short8){0, 0, 0, 0, 0, 0, 0, 0};
            if (k0 < XD) {
                const float* src = xg + (size_t)(m0 + row) * XD + k0;
                float4 f0 = *reinterpret_cast<const float4*>(src);
                float4 f1 = *reinterpret_cast<const float4*>(src + 4);
                v8[0] = (short)bf16_(f0.x); v8[1] = (short)bf16_(f0.y);
                v8[2] = (short)bf16_(f0.z); v8[3] = (short)bf16_(f0.w);
                v8[4] = (short)bf16_(f1.x); v8[5] = (short)bf16_(f1.y);
                v8[6] = (short)bf16_(f1.z); v8[7] = (short)bf16_(f1.w);
            }
            const int rg = row >> 4;
            const int lane = (row & 15) + ((kc & 3) << 4);
            *reinterpret_cast<short8*>(&xs[((rg * 26 + (kc >> 2)) * 64 + lane) * 8]) = v8;
        }
    }
    if (tid < 256) reinterpret_cast<uint4*>(fbL)[tid] = (uint4){0u, 0u, 0u, 0u};
    __syncthreads();

    layerS<0, 832, 13, 3>(tid, xs, xs, w1t, eb1, actP, nullptr, nullptr, nullptr, nullptr, ring);
    __syncthreads();
    layerS<0, 320, 5, 3>(tid, xs, actP, w2t, eb2, actQ, nullptr, nullptr, nullptr, nullptr, ring);
    __syncthreads();
    layerS<1, 320, 5, 1>(tid, xs, actQ, w3t, eb3, nullptr, c3L, nullptr, nullptr, nullptr, ring);
    __syncthreads();

    if (tid < 32) {
        float a = 0.f;
        #pragma unroll
        for (int j = 0; j < ZD; ++j) {
            float qm = c3L[tid * 24 + j];
            float qh = c3L[tid * 24 + 10 + j];
            float qv = sp_(qh) + 1e-8f;
            float e  = eps[(size_t)(m0 + tid) * ZD + j];
            float zj = qm + sqrtf(qv) * e;
            fbw(fbL, tid, j,      bf16_(zj * zj));
            fbw(fbL, tid, 10 + j, bf16_(zj));
            float d = zj - qm;
            a += __logf(6.283185307179586f * qv) + d * d / qv;
        }
        fbw(fbL, tid, 20, bf16_(1.f));   // picks up c_k hi/lo from G cols 20/21
        fbw(fbL, tid, 21, bf16_(1.f));
        lqzL[tid] = -0.5f * a;
    }
    __syncthreads();

    layerS<0, 64, 1, 3>(tid, xs, fbL, d1t, db1, actP, nullptr, nullptr, nullptr, nullptr, ring);
    __syncthreads();
    layerS<0, 320, 5, 3>(tid, xs, actP, d2t, db2, actQ, nullptr, nullptr, nullptr, nullptr, ring);
    __syncthreads();
    layerS<2, 320, 5, 7>(tid, xs, actQ, d3t, db3, nullptr, nullptr, redL, nullptr, nullptr, ring);
    __syncthreads();
    layerS<3, 64, 1, 16>(tid, xs, fbL, G, nullptr, nullptr, nullptr, nullptr, redM, redS, ring);
    __syncthreads();

    if (tid < 32) {
        float M = -1e30f, S = 0.f;
        #pragma unroll
        for (int w8 = 0; w8 < 8; ++w8) {
            float m = redM[tid * 8 + w8], s = redS[tid * 8 + w8];
            float M2 = fmaxf(M, m);
            S = S * __expf(M - M2) + s * __expf(m - M2);
            M = M2;
        }
        float lpz = M + __logf(S) - 7.6009024595420824f;  // log(2000)
        float lpx = 0.f;
        #pragma unroll
        for (int w8 = 0; w8 < 8; ++w8) lpx += redL[tid * 8 + w8];
        float kl = lqzL[tid] - lpz;
        float ne = kl - lpx, re = -lpx;
        #pragma unroll
        for (int d = 1; d <= 16; d <<= 1) {
            ne += __shfl_xor(ne, d); kl += __shfl_xor(kl, d); re += __shfl_xor(re, d);
        }
        if (tid == 0) {
            part[blockIdx.x * 3 + 0] = ne;
            part[blockIdx.x * 3 + 1] = kl;
            part[blockIdx.x * 3 + 2] = re;
        }
    }
}

// weight transposes/pads + GMM coef matrix (c_k folded as bf16 hi/lo cols)
__global__ __launch_bounds__(256)
void prep_k(const float* __restrict__ ew1, const float* __restrict__ ew2,
            const float* __restrict__ ew3, const float* __restrict__ dw1,
            const float* __restrict__ dw2, const float* __restrict__ dw3,
            const float* __restrict__ zpre,
            unsigned short* __restrict__ w1t, unsigned short* __restrict__ w2t,
            unsigned short* __restrict__ w3t, unsigned short* __restrict__ d1t,
            unsigned short* __restrict__ d2t, unsigned short* __restrict__ d3t,
            unsigned short* __restrict__ G)
{
    const int idx = blockIdx.x * 256 + threadIdx.x;
    const int y = blockIdx.y;
    if (y == 0) {
        if (idx >= 384 * 832) return;
        int n = idx / 832, k = idx - n * 832;
        w1t[idx] = bf16_((n < HH && k < XD) ? ew1[(size_t)k * HH + n] : 0.f);
    } else if (y == 1) {
        if (idx >= 384 * 320) return;
        int n = idx / 320, k = idx - n * 320;
        w2t[idx] = bf16_((n < HH && k < HH) ? ew2[(size_t)k * HH + n] : 0.f);
    } else if (y == 2) {
        if (idx >= 128 * 320) return;
        int n = idx / 320, k = idx - n * 320;
        w3t[idx] = bf16_((n < 2 * ZD && k < HH) ? ew3[(size_t)k * 2 * ZD + n] : 0.f);
    } else if (y == 3) {   // d1t [384][64]; dw1 rows at k=10..19 (fb layout)
        if (idx >= 384 * 64) return;
        int n = idx / 64, k = idx - n * 64;
        float v = (n < HH && k >= 10 && k < 20) ? dw1[(size_t)(k - 10) * HH + n] : 0.f;
        d1t[idx] = bf16_(v);
    } else if (y == 4) {
        if (idx >= 384 * 320) return;
        int n = idx / 320, k = idx - n * 320;
        d2t[idx] = bf16_((n < HH && k < HH) ? dw2[(size_t)k * HH + n] : 0.f);
    } else if (y == 5) {
        if (idx >= 896 * 320) return;
        int n = idx / 320, k = idx - n * 320;
        d3t[idx] = bf16_((n < XD && k < HH) ? dw3[(size_t)k * XD + n] : 0.f);
    } else {
        if (idx >= 2048) return;
        int k = idx;
        if (k < KK) {
            float csum = 0.f;
            #pragma unroll
            for (int j = 0; j < ZD; ++j) {
                float m = zpre[k * ZD + j];
                float h = zpre[(KK + k) * ZD + j];
                float v = sp_(h) + 1e-8f;
                G[k * 64 + j] = bf16_(-0.5f / v);
                G[k * 64 + 10 + j] = bf16_(m / v);
                csum += __logf(6.283185307179586f * v) + m * m / v;
            }
            float ck = -0.5f * csum;
            unsigned short hic = bf16_(ck);
            G[k * 64 + 20] = hic;
            G[k * 64 + 21] = bf16_(ck - b2f_(hic));
            #pragma unroll
            for (int j = 22; j < 64; ++j) G[k * 64 + j] = 0;
        } else {
            #pragma unroll
            for (int j = 0; j < 20; ++j) G[k * 64 + j] = 0;
            G[k * 64 + 20] = bf16_(-1e30f);
            G[k * 64 + 21] = 0;
            #pragma unroll
            for (int j = 22; j < 64; ++j) G[k * 64 + j] = 0;
        }
    }
}

__global__ void fin_k(const float* __restrict__ part, float* __restrict__ out)
{
    int c = threadIdx.x >> 6, l = threadIdx.x & 63;
    if (c < 3) {
        float s = 0.f;
        for (int i = l; i < 256; i += 64) s += part[i * 3 + c];
        #pragma unroll
        for (int d = 1; d < 64; d <<= 1) s += __shfl_xor(s, d);
        if (l == 0) out[c] = s / (float)BB;
    }
}

extern "C" void kernel_launch(void* const* d_in, const int* in_sizes, int n_in,
                              void* d_out, int out_size, void* d_ws, size_t ws_size,
                              hipStream_t stream)
{
    const float* x    = (const float*)d_in[0];
    const float* eps  = (const float*)d_in[1];
    const float* zpre = (const float*)d_in[2];
    const float* ew1  = (const float*)d_in[3];
    const float* eb1  = (const float*)d_in[4];
    const float* ew2  = (const float*)d_in[5];
    const float* eb2  = (const float*)d_in[6];
    const float* ew3  = (const float*)d_in[7];
    const float* eb3  = (const float*)d_in[8];
    const float* dw1  = (const float*)d_in[9];
    const float* db1  = (const float*)d_in[10];
    const float* dw2  = (const float*)d_in[11];
    const float* db2  = (const float*)d_in[12];
    const float* dw3  = (const float*)d_in[13];
    const float* db3  = (const float*)d_in[14];
    float* out = (float*)d_out;

    float* ws   = (float*)d_ws;
    float* part = ws;                        // 256*3
    unsigned short* ub = (unsigned short*)(part + 768);
    unsigned short* w1t = ub; ub += 384 * 832;
    unsigned short* w2t = ub; ub += 384 * 320;
    unsigned short* w3t = ub; ub += 128 * 320;
    unsigned short* d1t = ub; ub += 384 * 64;
    unsigned short* d2t = ub; ub += 384 * 320;
    unsigned short* d3t = ub; ub += 896 * 320;
    unsigned short* G   = ub; ub += 2048 * 64;

    dim3 blk(256);
    prep_k<<<dim3(1248, 7), blk, 0, stream>>>(ew1, ew2, ew3, dw1, dw2, dw3, zpre,
                                              w1t, w2t, w3t, d1t, d2t, d3t, G);
    fused_k<<<256, 512, 0, stream>>>(x, w1t, eb1, w2t, eb2, w3t, eb3,
                                     d1t, db1, d2t, db2, d3t, db3, G, eps, part);
    fin_k<<<1, 256, 0, stream>>>(part, out);
}

// Round 18
// 62.697 us; speedup vs baseline: 2.5098x; 1.4490x over previous
//
#include <hip/hip_runtime.h>
#include <hip/hip_bf16.h>
#include <math.h>

#define BB 8192
#define XD 784
#define ZD 10
#define KK 2000
#define HH 300

typedef short short8 __attribute__((ext_vector_type(8)));
typedef float f32x4 __attribute__((ext_vector_type(4)));

__device__ __forceinline__ float sp_(float x) {
    return fmaxf(x, 0.f) + __logf(1.f + __expf(-fabsf(x)));
}
__device__ __forceinline__ float elu_(float x) { return x > 0.f ? x : __expf(x) - 1.f; }
__device__ __forceinline__ unsigned short bf16_(float v) {
    __hip_bfloat16 h = __float2bfloat16(v);
    return __builtin_bit_cast(unsigned short, h);
}
__device__ __forceinline__ float b2f_(unsigned short u) {
    return __builtin_bit_cast(float, (unsigned int)u << 16);
}
__device__ __forceinline__ short8 ld8_(const unsigned short* p) {
    return *reinterpret_cast<const short8*>(p);
}
__device__ __forceinline__ void gl16(const unsigned short* g, unsigned short* l) {
    __builtin_amdgcn_global_load_lds(
        (const __attribute__((address_space(1))) unsigned int*)g,
        (__attribute__((address_space(3))) unsigned int*)l, 16, 0, 0);
}
template<int N> __device__ __forceinline__ void vwait() {
    if constexpr (N == 0) asm volatile("s_waitcnt vmcnt(0)" ::: "memory");
    if constexpr (N == 2) asm volatile("s_waitcnt vmcnt(2)" ::: "memory");
    if constexpr (N == 4) asm volatile("s_waitcnt vmcnt(4)" ::: "memory");
    if constexpr (N == 6) asm volatile("s_waitcnt vmcnt(6)" ::: "memory");
}
// fragment-major write of element (row<32, k) into 2-rowgroup buffer, KS=2
__device__ __forceinline__ void fbw(unsigned short* fb, int row, int k, unsigned short v) {
    fb[(((row >> 4) * 2 + (k >> 5)) * 64 + (row & 15) + (((k >> 3) & 3) << 4)) * 8 + (k & 7)] = v;
}

// ---------------------------------------------------------------------------
// Unified streamed layer on a 32-row slab: C[32][NI*128] = A @ Wt^T.
// 8 waves, wave w owns cols {ni*128 + w*16..+15}. ni-outer / ki-inner, fully
// unrolled. Weights are FRAGMENT-MAJOR in global: chunk (nt,kc) = 1KB
// holding cols nt*16..+15 x k kc*32..+31, lane=cl+hi*16 -> a wave's step
// fragment is one CONTIGUOUS 2KB block; gl16 reads base+lane*16 (perfectly
// coalesced, 8 full 128B lines vs 16 half-used before). 3-slot wave-private
// LDS ring, prefetch distance 3, counted vmcnt, no intra-layer barriers.
// LMODE 0: bf16 elu -> actout. LMODE 1: fp32 c3L (c<20).
// LMODE 2: per-row sum(x*logit - softplus(logit)), x from LDS xs -> redL.
// LMODE 3: per-lane online logsumexp over ni -> redM/redS (c_k in cols 20/21).
// ---------------------------------------------------------------------------
template<int LMODE, int KP, int KI, int NI>
__device__ __forceinline__ void layerS(
    const int tid,
    const unsigned short* __restrict__ xs,
    const unsigned short* __restrict__ actin,
    const unsigned short* __restrict__ Wt,
    const float* __restrict__ bias,
    unsigned short* __restrict__ actout,
    float* __restrict__ c3L, float* __restrict__ redL,
    float* __restrict__ redM, float* __restrict__ redS,
    unsigned short* __restrict__ ring)
{
    const int w = tid >> 6, l = tid & 63;
    const int cl = l & 15, hi = l >> 4, g4 = hi << 2;
    constexpr int KS = KP / 32;        // k-chunks per nt (and act slices/rowgroup)
    constexpr int NQ = NI * KI;
    unsigned short* ringW = ring + w * 3072;               // 3 slots x 1024 sh
    const unsigned short* bsrc = Wt + l * 8;

    f32x4 acc[2];
    float rA[2][4], rB[2][4];
    #pragma unroll
    for (int rg = 0; rg < 2; ++rg)
        #pragma unroll
        for (int rr = 0; rr < 4; ++rr) {
            rA[rg][rr] = (LMODE == 3) ? -1e30f : 0.f;
            rB[rg][rr] = 0.f;
        }

    auto STAGE = [&](int q) {
        const int ni = q / KI, ki = q % KI, slot = q % 3;
        const unsigned short* s0 = bsrc + (((size_t)(ni * 8 + w) * KS + 2 * ki) << 9);
        gl16(s0,       ringW + slot * 1024);
        gl16(s0 + 512, ringW + slot * 1024 + 512);
    };

    STAGE(0);
    if constexpr (NQ > 1) STAGE(1);
    if constexpr (NQ > 2) STAGE(2);

    #pragma unroll
    for (int q = 0; q < NQ; ++q) {
        const int ni = q / KI, ki = q % KI, slot = q % 3;
        if (ki == 0) {
            acc[0] = (f32x4){0.f, 0.f, 0.f, 0.f};
            acc[1] = (f32x4){0.f, 0.f, 0.f, 0.f};
        }
        const int rem = NQ - 1 - q;
        if (rem >= 3) vwait<6>();
        else if (rem == 2) vwait<4>();
        else if (rem == 1) vwait<2>();
        else vwait<0>();
        __builtin_amdgcn_sched_barrier(0);
        short8 b0 = ld8_(ringW + slot * 1024 + l * 8);
        short8 b1 = ld8_(ringW + slot * 1024 + 512 + l * 8);
        short8 a00 = ld8_(actin + ((0 * KS + ki * 2 + 0) * 64 + l) * 8);
        short8 a01 = ld8_(actin + ((0 * KS + ki * 2 + 1) * 64 + l) * 8);
        short8 a10 = ld8_(actin + ((1 * KS + ki * 2 + 0) * 64 + l) * 8);
        short8 a11 = ld8_(actin + ((1 * KS + ki * 2 + 1) * 64 + l) * 8);
        if (q + 3 < NQ) STAGE(q + 3);      // same slot, after its reads issued
        acc[0] = __builtin_amdgcn_mfma_f32_16x16x32_bf16(a00, b0, acc[0], 0, 0, 0);
        acc[0] = __builtin_amdgcn_mfma_f32_16x16x32_bf16(a01, b1, acc[0], 0, 0, 0);
        acc[1] = __builtin_amdgcn_mfma_f32_16x16x32_bf16(a10, b0, acc[1], 0, 0, 0);
        acc[1] = __builtin_amdgcn_mfma_f32_16x16x32_bf16(a11, b1, acc[1], 0, 0, 0);

        if (ki == KI - 1) {
            const int c = ni * 128 + w * 16 + cl;
            if constexpr (LMODE == 0) {
                const float bb = (c < HH) ? bias[c] : 0.f;
                #pragma unroll
                for (int rg = 0; rg < 2; ++rg)
                    #pragma unroll
                    for (int rr = 0; rr < 4; ++rr) {
                        float o = (c < HH) ? elu_(acc[rg][rr] + bb) : 0.f;
                        if (c < 320)
                            actout[((rg * 10 + (c >> 5)) * 64 + (g4 + rr) + (((c >> 3) & 3) << 4)) * 8 + (c & 7)] = bf16_(o);
                    }
            } else if constexpr (LMODE == 1) {
                const int cc = w * 16 + cl;
                if (cc < 20) {
                    #pragma unroll
                    for (int rg = 0; rg < 2; ++rg)
                        #pragma unroll
                        for (int rr = 0; rr < 4; ++rr)
                            c3L[(rg * 16 + g4 + rr) * 24 + cc] = acc[rg][rr] + bias[cc];
                }
            } else if constexpr (LMODE == 2) {
                if (c < XD) {
                    const float bb = bias[c];
                    #pragma unroll
                    for (int rg = 0; rg < 2; ++rg)
                        #pragma unroll
                        for (int rr = 0; rr < 4; ++rr) {
                            float lv = acc[rg][rr] + bb;
                            float xv = b2f_(xs[((rg * 26 + (c >> 5)) * 64 + (g4 + rr) + (((c >> 3) & 3) << 4)) * 8 + (c & 7)]);
                            rA[rg][rr] += xv * lv - sp_(lv);
                        }
                }
            } else {
                #pragma unroll
                for (int rg = 0; rg < 2; ++rg)
                    #pragma unroll
                    for (int rr = 0; rr < 4; ++rr) {
                        float v = acc[rg][rr];
                        float mx = fmaxf(v, rA[rg][rr]);
                        rB[rg][rr] = rB[rg][rr] * __expf(rA[rg][rr] - mx) + __expf(v - mx);
                        rA[rg][rr] = mx;
                    }
            }
        }
    }

    if constexpr (LMODE == 2) {
        #pragma unroll
        for (int rg = 0; rg < 2; ++rg)
            #pragma unroll
            for (int rr = 0; rr < 4; ++rr) {
                float s = rA[rg][rr];
                s += __shfl_xor(s, 1); s += __shfl_xor(s, 2);
                s += __shfl_xor(s, 4); s += __shfl_xor(s, 8);
                if (cl == 0) redL[(rg * 16 + g4 + rr) * 8 + w] = s;
            }
    }
    if constexpr (LMODE == 3) {
        #pragma unroll
        for (int d = 1; d <= 8; d <<= 1)
            #pragma unroll
            for (int rg = 0; rg < 2; ++rg)
                #pragma unroll
                for (int rr = 0; rr < 4; ++rr) {
                    float mo = __shfl_xor(rA[rg][rr], d);
                    float so = __shfl_xor(rB[rg][rr], d);
                    float M = fmaxf(rA[rg][rr], mo);
                    rB[rg][rr] = rB[rg][rr] * __expf(rA[rg][rr] - M) + so * __expf(mo - M);
                    rA[rg][rr] = M;
                }
        if (cl == 0) {
            #pragma unroll
            for (int rg = 0; rg < 2; ++rg)
                #pragma unroll
                for (int rr = 0; rr < 4; ++rr) {
                    redM[(rg * 16 + g4 + rr) * 8 + w] = rA[rg][rr];
                    redS[(rg * 16 + g4 + rr) * 8 + w] = rB[rg][rr];
                }
        }
    }
}

__global__ __launch_bounds__(512, 2)
void fused_k(const float* __restrict__ xg,
             const unsigned short* __restrict__ w1t, const float* __restrict__ eb1,
             const unsigned short* __restrict__ w2t, const float* __restrict__ eb2,
             const unsigned short* __restrict__ w3t, const float* __restrict__ eb3,
             const unsigned short* __restrict__ d1t, const float* __restrict__ db1,
             const unsigned short* __restrict__ d2t, const float* __restrict__ db2,
             const unsigned short* __restrict__ d3t, const float* __restrict__ db3,
             const unsigned short* __restrict__ G,
             const float* __restrict__ eps, float* __restrict__ part)
{
    __shared__ __align__(16) unsigned short xs[26624];    // 32x832 bf16 frag-major
    __shared__ __align__(16) unsigned short actP[10240];  // 32x320
    __shared__ __align__(16) unsigned short actQ[10240];
    __shared__ __align__(16) unsigned short fbL[2048];    // 32x64
    __shared__ __align__(16) unsigned short ring[24576];  // 8 waves x 3 slots x 1024
    __shared__ float c3L[768];
    __shared__ float redM[256], redS[256], redL[256], lqzL[32];

    const int tid = threadIdx.x;
    const int m0 = blockIdx.x * 32;

    // stage x (fp32 -> bf16, fragment-major); zero ALL of fbL (4096B = 256 uint4)
    #pragma unroll
    for (int it = 0; it < 7; ++it) {
        const int c = tid + it * 512;
        if (c < 32 * 104) {
            const int row = c / 104, kc = c - row * 104;
            const int k0 = kc * 8;
            short8 v8 = (short8){0, 0, 0, 0, 0, 0, 0, 0};
            if (k0 < XD) {
                const float* src = xg + (size_t)(m0 + row) * XD + k0;
                float4 f0 = *reinterpret_cast<const float4*>(src);
                float4 f1 = *reinterpret_cast<const float4*>(src + 4);
                v8[0] = (short)bf16_(f0.x); v8[1] = (short)bf16_(f0.y);
                v8[2] = (short)bf16_(f0.z); v8[3] = (short)bf16_(f0.w);
                v8[4] = (short)bf16_(f1.x); v8[5] = (short)bf16_(f1.y);
                v8[6] = (short)bf16_(f1.z); v8[7] = (short)bf16_(f1.w);
            }
            const int rg = row >> 4;
            const int lane = (row & 15) + ((kc & 3) << 4);
            *reinterpret_cast<short8*>(&xs[((rg * 26 + (kc >> 2)) * 64 + lane) * 8]) = v8;
        }
    }
    if (tid < 256) reinterpret_cast<uint4*>(fbL)[tid] = (uint4){0u, 0u, 0u, 0u};
    __syncthreads();

    layerS<0, 832, 13, 3>(tid, xs, xs, w1t, eb1, actP, nullptr, nullptr, nullptr, nullptr, ring);
    __syncthreads();
    layerS<0, 320, 5, 3>(tid, xs, actP, w2t, eb2, actQ, nullptr, nullptr, nullptr, nullptr, ring);
    __syncthreads();
    layerS<1, 320, 5, 1>(tid, xs, actQ, w3t, eb3, nullptr, c3L, nullptr, nullptr, nullptr, ring);
    __syncthreads();

    if (tid < 32) {
        float a = 0.f;
        #pragma unroll
        for (int j = 0; j < ZD; ++j) {
            float qm = c3L[tid * 24 + j];
            float qh = c3L[tid * 24 + 10 + j];
            float qv = sp_(qh) + 1e-8f;
            float e  = eps[(size_t)(m0 + tid) * ZD + j];
            float zj = qm + sqrtf(qv) * e;
            fbw(fbL, tid, j,      bf16_(zj * zj));
            fbw(fbL, tid, 10 + j, bf16_(zj));
            float d = zj - qm;
            a += __logf(6.283185307179586f * qv) + d * d / qv;
        }
        fbw(fbL, tid, 20, bf16_(1.f));   // picks up c_k hi/lo from G cols 20/21
        fbw(fbL, tid, 21, bf16_(1.f));
        lqzL[tid] = -0.5f * a;
    }
    __syncthreads();

    layerS<0, 64, 1, 3>(tid, xs, fbL, d1t, db1, actP, nullptr, nullptr, nullptr, nullptr, ring);
    __syncthreads();
    layerS<0, 320, 5, 3>(tid, xs, actP, d2t, db2, actQ, nullptr, nullptr, nullptr, nullptr, ring);
    __syncthreads();
    layerS<2, 320, 5, 7>(tid, xs, actQ, d3t, db3, nullptr, nullptr, redL, nullptr, nullptr, ring);
    __syncthreads();
    layerS<3, 64, 1, 16>(tid, xs, fbL, G, nullptr, nullptr, nullptr, nullptr, redM, redS, ring);
    __syncthreads();

    if (tid < 32) {
        float M = -1e30f, S = 0.f;
        #pragma unroll
        for (int w8 = 0; w8 < 8; ++w8) {
            float m = redM[tid * 8 + w8], s = redS[tid * 8 + w8];
            float M2 = fmaxf(M, m);
            S = S * __expf(M - M2) + s * __expf(m - M2);
            M = M2;
        }
        float lpz = M + __logf(S) - 7.6009024595420824f;  // log(2000)
        float lpx = 0.f;
        #pragma unroll
        for (int w8 = 0; w8 < 8; ++w8) lpx += redL[tid * 8 + w8];
        float kl = lqzL[tid] - lpz;
        float ne = kl - lpx, re = -lpx;
        #pragma unroll
        for (int d = 1; d <= 16; d <<= 1) {
            ne += __shfl_xor(ne, d); kl += __shfl_xor(kl, d); re += __shfl_xor(re, d);
        }
        if (tid == 0) {
            part[blockIdx.x * 3 + 0] = ne;
            part[blockIdx.x * 3 + 1] = kl;
            part[blockIdx.x * 3 + 2] = re;
        }
    }
}

// ---------------------------------------------------------------------------
// prep: weights -> FRAGMENT-MAJOR bf16 [NT][KS][64 lanes][8]:
// chunk (nt,kc) holds col n = nt*16+(lane&15), k = kc*32+(lane>>4)*8+e.
// Thread t writes one 16B lane-chunk (coalesced). GMM coefs computed
// directly in this layout (c_k hi/lo at k=20/21).
// ---------------------------------------------------------------------------
__global__ __launch_bounds__(256)
void prep_k(const float* __restrict__ ew1, const float* __restrict__ ew2,
            const float* __restrict__ ew3, const float* __restrict__ dw1,
            const float* __restrict__ dw2, const float* __restrict__ dw3,
            const float* __restrict__ zpre,
            unsigned short* __restrict__ w1t, unsigned short* __restrict__ w2t,
            unsigned short* __restrict__ w3t, unsigned short* __restrict__ d1t,
            unsigned short* __restrict__ d2t, unsigned short* __restrict__ d3t,
            unsigned short* __restrict__ G)
{
    const int t = blockIdx.x * 256 + threadIdx.x;
    const int y = blockIdx.y;
    const int lane = t & 63, chunk = t >> 6;
    const int cl = lane & 15, hi = lane >> 4;

    auto genw = [&](const float* W, unsigned short* out, int NT, int KS2,
                    int K, int N) {
        if (chunk >= NT * KS2) return;
        const int kc = chunk % KS2, nt = chunk / KS2;
        const int n = nt * 16 + cl, kb = kc * 32 + hi * 8;
        short8 v8;
        #pragma unroll
        for (int e = 0; e < 8; ++e) {
            const int k = kb + e;
            v8[e] = (short)bf16_((n < N && k < K) ? W[(size_t)k * N + n] : 0.f);
        }
        *reinterpret_cast<short8*>(&out[(size_t)t * 8]) = v8;
    };

    if (y == 0) genw(ew1, w1t, 24, 26, XD, HH);
    else if (y == 1) genw(ew2, w2t, 24, 10, HH, HH);
    else if (y == 2) genw(ew3, w3t, 8, 10, HH, 2 * ZD);
    else if (y == 3) {          // d1t: rows k=10..19 hold dw1 (fb layout)
        if (chunk >= 24 * 2) return;
        const int kc = chunk & 1, nt = chunk >> 1;
        const int n = nt * 16 + cl, kb = kc * 32 + hi * 8;
        short8 v8;
        #pragma unroll
        for (int e = 0; e < 8; ++e) {
            const int k = kb + e;
            float v = (n < HH && k >= 10 && k < 20) ? dw1[(size_t)(k - 10) * HH + n] : 0.f;
            v8[e] = (short)bf16_(v);
        }
        *reinterpret_cast<short8*>(&d1t[(size_t)t * 8]) = v8;
    }
    else if (y == 4) genw(dw2, d2t, 24, 10, HH, HH);
    else if (y == 5) genw(dw3, d3t, 56, 10, HH, XD);
    else {                      // G: NT=128, KS2=2; c_k hi/lo at k=20/21
        if (chunk >= 128 * 2) return;
        const int kc = chunk & 1, nt = chunk >> 1;
        const int n = nt * 16 + cl, kb = kc * 32 + hi * 8;
        float ck = 0.f;
        if (n < KK && kb == 16) {
            float csum = 0.f;
            #pragma unroll
            for (int j = 0; j < ZD; ++j) {
                float m = zpre[n * ZD + j];
                float h = zpre[(KK + n) * ZD + j];
                float v = sp_(h) + 1e-8f;
                csum += __logf(6.283185307179586f * v) + m * m / v;
            }
            ck = -0.5f * csum;
        }
        short8 v8;
        #pragma unroll
        for (int e = 0; e < 8; ++e) {
            const int k = kb + e;
            unsigned short us = 0;
            if (n < KK) {
                if (k < 10) {
                    float h = zpre[(KK + n) * ZD + k];
                    float v = sp_(h) + 1e-8f;
                    us = bf16_(-0.5f / v);
                } else if (k < 20) {
                    float m = zpre[n * ZD + (k - 10)];
                    float h = zpre[(KK + n) * ZD + (k - 10)];
                    float v = sp_(h) + 1e-8f;
                    us = bf16_(m / v);
                } else if (k == 20) {
                    us = bf16_(ck);
                } else if (k == 21) {
                    us = bf16_(ck - b2f_(bf16_(ck)));
                }
            } else if (k == 20) {
                us = bf16_(-1e30f);
            }
            v8[e] = (short)us;
        }
        *reinterpret_cast<short8*>(&G[(size_t)t * 8]) = v8;
    }
}

__global__ void fin_k(const float* __restrict__ part, float* __restrict__ out)
{
    int c = threadIdx.x >> 6, l = threadIdx.x & 63;
    if (c < 3) {
        float s = 0.f;
        for (int i = l; i < 256; i += 64) s += part[i * 3 + c];
        #pragma unroll
        for (int d = 1; d < 64; d <<= 1) s += __shfl_xor(s, d);
        if (l == 0) out[c] = s / (float)BB;
    }
}

extern "C" void kernel_launch(void* const* d_in, const int* in_sizes, int n_in,
                              void* d_out, int out_size, void* d_ws, size_t ws_size,
                              hipStream_t stream)
{
    const float* x    = (const float*)d_in[0];
    const float* eps  = (const float*)d_in[1];
    const float* zpre = (const float*)d_in[2];
    const float* ew1  = (const float*)d_in[3];
    const float* eb1  = (const float*)d_in[4];
    const float* ew2  = (const float*)d_in[5];
    const float* eb2  = (const float*)d_in[6];
    const float* ew3  = (const float*)d_in[7];
    const float* eb3  = (const float*)d_in[8];
    const float* dw1  = (const float*)d_in[9];
    const float* db1  = (const float*)d_in[10];
    const float* dw2  = (const float*)d_in[11];
    const float* db2  = (const float*)d_in[12];
    const float* dw3  = (const float*)d_in[13];
    const float* db3  = (const float*)d_in[14];
    float* out = (float*)d_out;

    float* ws   = (float*)d_ws;
    float* part = ws;                        // 256*3
    unsigned short* ub = (unsigned short*)(part + 768);
    unsigned short* w1t = ub; ub += 24 * 26 * 512;   // 384x832
    unsigned short* w2t = ub; ub += 24 * 10 * 512;   // 384x320
    unsigned short* w3t = ub; ub += 8 * 10 * 512;    // 128x320
    unsigned short* d1t = ub; ub += 24 * 2 * 512;    // 384x64
    unsigned short* d2t = ub; ub += 24 * 10 * 512;   // 384x320
    unsigned short* d3t = ub; ub += 56 * 10 * 512;   // 896x320
    unsigned short* G   = ub; ub += 128 * 2 * 512;   // 2048x64

    dim3 blk(256);
    prep_k<<<dim3(156, 7), blk, 0, stream>>>(ew1, ew2, ew3, dw1, dw2, dw3, zpre,
                                             w1t, w2t, w3t, d1t, d2t, d3t, G);
    fused_k<<<256, 512, 0, stream>>>(x, w1t, eb1, w2t, eb2, w3t, eb3,
                                     d1t, db1, d2t, db2, d3t, db3, G, eps, part);
    fin_k<<<1, 256, 0, stream>>>(part, out);
}